// Round 10
// baseline (64.907 us; speedup 1.0000x reference)
//
#include <hip/hip_runtime.h>
#include <math.h>

namespace {
constexpr int B = 4, N = 4, C = 64, H = 128, W = 256, L = 5;
constexpr int HW = H * W;
constexpr int WAVES = 8;          // waves per block
constexpr int CPW = C / WAVES;    // channels per wave = 8
}

// 8-byte pair load with only 4-byte alignment guarantee (x-taps are adjacent).
typedef float f2v __attribute__((ext_vector_type(2), aligned(4)));

__global__ __launch_bounds__(512, 2) void atten_comm_kernel(
    const float* __restrict__ x,    // (B*N, C, H, W)
    const float* __restrict__ P,    // (B, L, L, 4, 4)
    float* __restrict__ out)        // (B, C, H, W)
{
    __shared__ float sredA[WAVES][N][64];
    __shared__ float sredB[WAVES][N][64];

    const int b    = blockIdx.z;
    const int hA   = (int)(blockIdx.y << 1);
    const int hB   = hA + 1;
    const int lane = (int)(threadIdx.x & 63);
    const int wv   = (int)(threadIdx.x >> 6);
    const int w    = (blockIdx.x << 6) + lane;

    // normalized grid coords (align_corners=True)
    const float gx  = -1.0f + (2.0f / (float)(W - 1)) * (float)w;
    const float gyA = -1.0f + (2.0f / (float)(H - 1)) * (float)hA;
    const float gyB = -1.0f + (2.0f / (float)(H - 1)) * (float)hB;

    const float* basep[N];
    int   vA0[N], vA1[N], vB0[N], vB1[N];
    float uA0x[N], uA0y[N], uA1x[N], uA1y[N];
    float uB0x[N], uB0y[N], uB1x[N], uB1y[N];

    // taps: (ix,iy) -> pair-load offsets + folded bilinear/boundary weights
    auto taps = [](float ix, float iy, int& voff0, int& voff1,
                   float& u0x, float& u0y, float& u1x, float& u1y) {
        const float fx0 = floorf(ix);
        const float fy0 = floorf(iy);
        const int x0 = (int)fx0, y0 = (int)fy0;
        const int y1 = y0 + 1;
        const float wx = ix - fx0;
        const float wy = iy - fy0;

        const int   xa   = min(max(x0, 0), W - 2);
        const float wx0v = (1.0f - wx) * ((x0 >= 0 && x0 < W) ? 1.0f : 0.0f);
        const float wx1v = wx * ((x0 + 1 >= 0 && x0 + 1 < W) ? 1.0f : 0.0f);
        // interior: (wx0v,wx1v); x0==-1 -> (wx1v,0); x0==W-1 -> (0,wx0v)
        const float ux = (x0 < 0) ? wx1v : ((x0 > W - 2) ? 0.0f : wx0v);
        const float uy = (x0 < 0) ? 0.0f : ((x0 > W - 2) ? wx0v : wx1v);

        const int yc0 = min(max(y0, 0), H - 1);
        const int yc1 = min(max(y1, 0), H - 1);
        const float wyv0 = (1.0f - wy) * ((y0 >= 0 && y0 < H) ? 1.0f : 0.0f);
        const float wyv1 = wy * ((y1 >= 0 && y1 < H) ? 1.0f : 0.0f);

        u0x = ux * wyv0;  u0y = uy * wyv0;
        u1x = ux * wyv1;  u1y = uy * wyv1;
        voff0 = yc0 * W + xa;
        voff1 = yc1 * W + xa;
    };

#pragma unroll
    for (int n = 0; n < N; ++n) {
        // P[b, 0, n, r, c]; strides: b:L*L*16, i:L*16, j:16, r:4, c:1
        const float* p = P + ((size_t)b * L * L + (size_t)n) * 16;
        const float a  = p[0];
        const float bb = p[1] * ((float)H / (float)W);
        const float cc = p[3] * (2.0f / (4.0f * 0.4f * (float)W));
        const float d  = p[4] * ((float)W / (float)H);
        const float e  = p[5];
        const float ff = p[7] * (2.0f / (4.0f * 0.4f * (float)H));

        const float ixA = (a * gx + bb * gyA + cc + 1.0f) * (0.5f * (float)(W - 1));
        const float iyA = (d * gx + e * gyA + ff + 1.0f) * (0.5f * (float)(H - 1));
        const float ixB = (a * gx + bb * gyB + cc + 1.0f) * (0.5f * (float)(W - 1));
        const float iyB = (d * gx + e * gyB + ff + 1.0f) * (0.5f * (float)(H - 1));

        taps(ixA, iyA, vA0[n], vA1[n], uA0x[n], uA0y[n], uA1x[n], uA1y[n]);
        taps(ixB, iyB, vB0[n], vB1[n], uB0x[n], uB0y[n], uB1x[n], uB1y[n]);

        basep[n] = x + ((size_t)(b * N + n) * C + (size_t)(wv * CPW)) * HW;
    }

    // ---- gather: 16 pair-loads (2 pixels x 4 agents x 2 rows) per channel ----
    float fA[N][CPW], fB[N][CPW];
#pragma unroll
    for (int cc = 0; cc < CPW; ++cc) {
        f2v a0[N], a1[N], b0[N], b1[N];
#pragma unroll
        for (int n = 0; n < N; ++n) {
            const float* pl = basep[n] + (size_t)cc * HW;
            a0[n] = *(const f2v*)(pl + vA0[n]);
            a1[n] = *(const f2v*)(pl + vA1[n]);
            b0[n] = *(const f2v*)(pl + vB0[n]);
            b1[n] = *(const f2v*)(pl + vB1[n]);
        }
#pragma unroll
        for (int n = 0; n < N; ++n) {
            fA[n][cc] = uA0x[n] * a0[n].x + uA0y[n] * a0[n].y
                      + uA1x[n] * a1[n].x + uA1y[n] * a1[n].y;
            fB[n][cc] = uB0x[n] * b0[n].x + uB0y[n] * b0[n].y
                      + uB1x[n] * b1[n].x + uB1y[n] * b1[n].y;
        }
    }

    // ---- partial scores over this wave's channels ----
    float sA[N] = {0.f, 0.f, 0.f, 0.f};
    float sB[N] = {0.f, 0.f, 0.f, 0.f};
#pragma unroll
    for (int cc = 0; cc < CPW; ++cc) {
        const float qA = fA[0][cc];
        const float qB = fB[0][cc];
#pragma unroll
        for (int n = 0; n < N; ++n) {
            sA[n] += qA * fA[n][cc];
            sB[n] += qB * fB[n][cc];
        }
    }

    // ---- cross-wave reduction via LDS (lane-stride-1, conflict-free) ----
#pragma unroll
    for (int n = 0; n < N; ++n) {
        sredA[wv][n][lane] = sA[n];
        sredB[wv][n][lane] = sB[n];
    }
    __syncthreads();

    float stA[N], stB[N];
#pragma unroll
    for (int n = 0; n < N; ++n) {
        float accA = 0.f, accB = 0.f;
#pragma unroll
        for (int v = 0; v < WAVES; ++v) {
            accA += sredA[v][n][lane];
            accB += sredB[v][n][lane];
        }
        stA[n] = accA;
        stB[n] = accB;
    }

    const float scale = 0.125f;  // 1/sqrt(64)
    float attnA[N], attnB[N];
    {
        const float s0 = stA[0] * scale, s1 = stA[1] * scale;
        const float s2 = stA[2] * scale, s3 = stA[3] * scale;
        const float m  = fmaxf(fmaxf(s0, s1), fmaxf(s2, s3));
        const float e0 = expf(s0 - m), e1 = expf(s1 - m);
        const float e2 = expf(s2 - m), e3 = expf(s3 - m);
        const float inv = 1.0f / (e0 + e1 + e2 + e3);
        attnA[0] = e0 * inv; attnA[1] = e1 * inv;
        attnA[2] = e2 * inv; attnA[3] = e3 * inv;
    }
    {
        const float s0 = stB[0] * scale, s1 = stB[1] * scale;
        const float s2 = stB[2] * scale, s3 = stB[3] * scale;
        const float m  = fmaxf(fmaxf(s0, s1), fmaxf(s2, s3));
        const float e0 = expf(s0 - m), e1 = expf(s1 - m);
        const float e2 = expf(s2 - m), e3 = expf(s3 - m);
        const float inv = 1.0f / (e0 + e1 + e2 + e3);
        attnB[0] = e0 * inv; attnB[1] = e1 * inv;
        attnB[2] = e2 * inv; attnB[3] = e3 * inv;
    }

    // ---- context from registers + coalesced stores (two rows) ----
    float* opA = out + ((size_t)b * C + (size_t)(wv * CPW)) * HW
                     + (size_t)hA * W + (size_t)w;
    float* opB = opA + W;
#pragma unroll
    for (int cc = 0; cc < CPW; ++cc) {
        float ctxA = 0.f, ctxB = 0.f;
#pragma unroll
        for (int n = 0; n < N; ++n) {
            ctxA += attnA[n] * fA[n][cc];
            ctxB += attnB[n] * fB[n][cc];
        }
        opA[(size_t)cc * HW] = ctxA;
        opB[(size_t)cc * HW] = ctxB;
    }
}

extern "C" void kernel_launch(void* const* d_in, const int* in_sizes, int n_in,
                              void* d_out, int out_size, void* d_ws, size_t ws_size,
                              hipStream_t stream) {
    const float* x  = (const float*)d_in[0];
    const float* P  = (const float*)d_in[1];
    float* out = (float*)d_out;

    dim3 block(512, 1, 1);
    dim3 grid(W / 64, H / 2, B);  // (4, 64, 4) = 1024 blocks
    hipLaunchKernelGGL(atten_comm_kernel, grid, block, 0, stream, x, P, out);
}